// Round 7
// baseline (258.962 us; speedup 1.0000x reference)
//
#include <hip/hip_runtime.h>
#include <hip/hip_bf16.h>

#define BIGF 99999999.0f
#define NPP 4096
#define BB 4
#define NQ 8
#define CAP 128

// ---------- helpers ----------

template <typename T>
__device__ __forceinline__ T bitonic_sort64(T v, int lane) {
    #pragma unroll
    for (int k = 2; k <= 64; k <<= 1) {
        #pragma unroll
        for (int j = k >> 1; j > 0; j >>= 1) {
            T p = __shfl_xor(v, j);
            bool up  = ((lane & k) == 0);
            bool low = ((lane & j) == 0);
            T mn = (v < p) ? v : p;
            T mx = (v < p) ? p : v;
            v = (up == low) ? mn : mx;
        }
    }
    return v;
}

// ---------- kernel 0: per-point squared norms + z projections + zero zout ----------

__global__ __launch_bounds__(256) void n2_kernel(
    const float* __restrict__ x, const float* __restrict__ z,
    const float* __restrict__ Wmz, const float* __restrict__ bmz,
    const float* __restrict__ Wvz, const float* __restrict__ bvz,
    float* __restrict__ n2tab, float* __restrict__ zzm, float* __restrict__ zzv,
    float* __restrict__ zout)
{
    int i = blockIdx.x * 256 + threadIdx.x;       // 0..16383
    const float4* p = (const float4*)(x + (long)i * 8);
    float4 a = p[0], c = p[1];
    float s = 0.f;
    s = fmaf(a.x, a.x, s); s = fmaf(a.y, a.y, s);
    s = fmaf(a.z, a.z, s); s = fmaf(a.w, a.w, s);
    s = fmaf(c.x, c.x, s); s = fmaf(c.y, c.y, s);
    s = fmaf(c.z, c.z, s); s = fmaf(c.w, c.w, s);
    n2tab[i] = s;

    if (blockIdx.x == 0) {
        zout[threadIdx.x] = 0.f;                  // 256 floats
        int b = threadIdx.x >> 6, l = threadIdx.x & 63;
        float sv = 0.f;
        for (int q = 0; q < 64; ++q) sv = fmaf(z[b * 64 + q], Wvz[q * 64 + l], sv);
        zzv[b * 64 + l] = sv + bvz[l];
        if (threadIdx.x < 32) {
            int bm = threadIdx.x >> 3, lm = threadIdx.x & 7;
            float sm = 0.f;
            for (int q = 0; q < 64; ++q) sm = fmaf(z[bm * 64 + q], Wmz[q * 8 + lm], sm);
            zzm[bm * 8 + lm] = sm + bmz[lm];
        }
    }
}

// ---------- kernel 1: exact knn top-16, NQ=8 queries per wave ----------
// Pass A: per-lane u32 key min over the lane's 64-candidate substream;
// u32 bitonic sort of the 64 lane-minima -> T = 16th smallest (16 distinct
// lane witnesses <= T, so {key <= T} contains the exact top-16).
// Pass B: recompute keys (bit-identical fmaf chain), wave __any early-out,
// rare LDS atomic-append of (key<<32)|j; final u64 bitonic sort (2-chunk
// merge if count>64) -> exact top-16 ascending, reference tie order.

__global__ __launch_bounds__(256) void knn_kernel(const float* __restrict__ x,
                                                  const float* __restrict__ n2tab,
                                                  int* __restrict__ idx_out) {
    __shared__ unsigned long long cand[4][NQ][CAP];   // 32 KB
    __shared__ unsigned cnt_s[4][NQ];

    int lane = threadIdx.x & 63;
    int wid  = threadIdx.x >> 6;
    if (lane < NQ) cnt_s[wid][lane] = 0;              // per-wave buffer

    int gw   = blockIdx.x * 4 + wid;      // 0..2047
    int q0   = gw * NQ;                   // 0..16376
    int b    = q0 >> 12;
    int qloc = q0 & 4095;
    const float* xb = x + (long)b * NPP * 8;
    const float* nb = n2tab + b * NPP;

    float qf[NQ][8];
    float n2i[NQ];
    int selfT[NQ], selfL[NQ];
    #pragma unroll
    for (int q = 0; q < NQ; ++q) {
        #pragma unroll
        for (int f = 0; f < 8; ++f) qf[q][f] = xb[(qloc + q) * 8 + f];
        n2i[q]   = nb[qloc + q];
        selfT[q] = (qloc + q) >> 6;
        selfL[q] = (qloc + q) & 63;
    }
    const unsigned BIGB = __float_as_uint(BIGF);

    // ---- pass A: per-lane u32 key min ----
    unsigned minb[NQ];
    #pragma unroll
    for (int q = 0; q < NQ; ++q) minb[q] = 0xFFFFFFFFu;

    #pragma unroll 2
    for (int t = 0; t < 64; ++t) {
        int j = t * 64 + lane;
        const float4* pj = (const float4*)(xb + (long)j * 8);
        float4 a = pj[0], c = pj[1];
        float n2j = nb[j];
        #pragma unroll
        for (int q = 0; q < NQ; ++q) {
            float dot = 0.f;
            dot = fmaf(qf[q][0], a.x, dot); dot = fmaf(qf[q][1], a.y, dot);
            dot = fmaf(qf[q][2], a.z, dot); dot = fmaf(qf[q][3], a.w, dot);
            dot = fmaf(qf[q][4], c.x, dot); dot = fmaf(qf[q][5], c.y, dot);
            dot = fmaf(qf[q][6], c.z, dot); dot = fmaf(qf[q][7], c.w, dot);
            float d2 = fmaf(-2.0f, dot, n2i[q] + n2j);
            unsigned kb = (d2 <= 0.0f) ? BIGB : __float_as_uint(d2);
            if (t == selfT[q]) {                       // uniform, 1-in-64
                kb = (lane == selfL[q]) ? BIGB : kb;
            }
            minb[q] = (kb < minb[q]) ? kb : minb[q];
        }
    }

    // thresholds: 16th smallest of the 64 lane minima
    unsigned T[NQ];
    #pragma unroll
    for (int q = 0; q < NQ; ++q) {
        unsigned s = bitonic_sort64(minb[q], lane);
        T[q] = (unsigned)__shfl((int)s, 15);
    }

    // ---- pass B: recompute + rare atomic append ----
    #pragma unroll 2
    for (int t = 0; t < 64; ++t) {
        int j = t * 64 + lane;
        const float4* pj = (const float4*)(xb + (long)j * 8);
        float4 a = pj[0], c = pj[1];
        float n2j = nb[j];
        unsigned kb[NQ];
        bool hit = false;
        #pragma unroll
        for (int q = 0; q < NQ; ++q) {
            float dot = 0.f;
            dot = fmaf(qf[q][0], a.x, dot); dot = fmaf(qf[q][1], a.y, dot);
            dot = fmaf(qf[q][2], a.z, dot); dot = fmaf(qf[q][3], a.w, dot);
            dot = fmaf(qf[q][4], c.x, dot); dot = fmaf(qf[q][5], c.y, dot);
            dot = fmaf(qf[q][6], c.z, dot); dot = fmaf(qf[q][7], c.w, dot);
            float d2 = fmaf(-2.0f, dot, n2i[q] + n2j);
            unsigned k = (d2 <= 0.0f) ? BIGB : __float_as_uint(d2);
            if (t == selfT[q]) {
                k = (lane == selfL[q]) ? BIGB : k;
            }
            kb[q] = k;
            hit |= (k <= T[q]);
        }
        if (__any(hit)) {
            #pragma unroll
            for (int q = 0; q < NQ; ++q) {
                if (kb[q] <= T[q]) {
                    unsigned old = atomicAdd(&cnt_s[wid][q], 1u);
                    if (old < CAP) {
                        cand[wid][q][old] =
                            ((unsigned long long)kb[q] << 32) | (unsigned)j;
                    }
                }
            }
        }
    }

    // ---- final: sort candidates, emit top-16 (append order irrelevant) ----
    #pragma unroll 1
    for (int q = 0; q < NQ; ++q) {
        unsigned nc = cnt_s[wid][q];
        int n = nc > CAP ? CAP : (int)nc;
        unsigned long long v = (lane < n) ? cand[wid][q][lane] : ~0ull;
        unsigned long long R = bitonic_sort64(v, lane);
        if (n > 64) {                                   // rare 2nd chunk
            unsigned long long w2 = (64 + lane < n) ? cand[wid][q][64 + lane] : ~0ull;
            w2 = bitonic_sort64(w2, lane);
            unsigned long long vt = __shfl(w2, lane - 16);
            unsigned long long comb = (lane < 16) ? R : ((lane < 32) ? vt : ~0ull);
            R = bitonic_sort64(comb, lane);
        }
        if (lane < 16) {
            idx_out[(long)(q0 + q) * 16 + lane] = (int)(R & 0xFFFFFFFFull);
        }
    }
}

// ---------- kernel 2: features + output heads ----------
// One wave per point. Stage1 writes m-moments AND v-moments to LDS
// (stride-68 rows, 16B aligned). Stage2: x-head via float4 LDS reads.
// Stage3: z-head via broadcast ds_read_b128 (no readlane).

__global__ __launch_bounds__(256) void feat_kernel(
    const float* __restrict__ x, const int* __restrict__ idxw,
    const float* __restrict__ Wm2, const float* __restrict__ bm2,
    const float* __restrict__ Wm3, const float* __restrict__ bm3,
    const float* __restrict__ Wv2, const float* __restrict__ bv2,
    const float* __restrict__ Wv3, const float* __restrict__ bv3,
    const float* __restrict__ Wmx, const float* __restrict__ bmx,
    const float* __restrict__ Wvx, const float* __restrict__ bvx,
    const float* __restrict__ zzm, const float* __restrict__ zzv,
    float* __restrict__ xout, float* __restrict__ zout)
{
    int lane = threadIdx.x & 63;
    int wid  = threadIdx.x >> 6;
    int pn   = blockIdx.x * 4 + wid;          // global point id
    int b    = pn >> 12;
    const float* xb = x + b * NPP * 8;

    __shared__ float xg_s[4][16][8];
    __shared__ float mo_s[4][15][68];         // cols 0..31 m-moments, 32..63 v-moments
    __shared__ float wmx_s[32][8];
    __shared__ float bzm_s[8];
    __shared__ float zpart[4][64];

    if (threadIdx.x < 256) {
        wmx_s[threadIdx.x >> 3][threadIdx.x & 7] = Wmx[threadIdx.x];
    }
    if (threadIdx.x < 8) bzm_s[threadIdx.x] = bmx[threadIdx.x] + zzm[b * 8 + threadIdx.x];

    int k = lane & 15;
    float w20 = Wm2[k], w21 = Wm2[16 + k], bb2 = bm2[k];
    float w30 = Wm3[k], w31 = Wm3[16 + k], w32 = Wm3[32 + k], bb3 = bm3[k];
    float u20 = Wv2[k], u21 = Wv2[16 + k], cc2 = bv2[k];
    float u30 = Wv3[k], u31 = Wv3[16 + k], u32 = Wv3[32 + k], cc3 = bv3[k];
    float wvx[32];
    #pragma unroll
    for (int c = 0; c < 32; ++c) wvx[c] = Wvx[c * 64 + lane];
    float bz3 = bvx[lane] + zzv[b * 64 + lane];

    if (lane < 16) {
        int myid = idxw[(long)pn * 16 + lane];
        const float4* ps = (const float4*)(xb + (long)myid * 8);
        float4 a = ps[0], c4 = ps[1];
        *((float4*)&xg_s[wid][lane][0]) = a;
        *((float4*)&xg_s[wid][lane][4]) = c4;
    }
    __syncthreads();

    float g0[8];
    #pragma unroll
    for (int f = 0; f < 8; ++f) g0[f] = xg_s[wid][0][f];

    // stage 1: moments (mean over d folded as exact *0.125)
    #pragma unroll
    for (int p = 0; p < 4; ++p) {
        int rg = lane >> 4;
        int r  = p * 4 + rg;
        int rc = (r < 14) ? r : 14;
        int i2  = rc + 1;
        int i3a = (rc < 14) ? 1 : 2;
        int i3b = (rc < 14) ? rc + 2 : 3;
        const float* G1  = xg_s[wid][i2];
        const float* G3a = xg_s[wid][i3a];
        const float* G3b = xg_s[wid][i3b];
        float s2 = 0.f, s3 = 0.f, t2 = 0.f, t3 = 0.f;
        #pragma unroll
        for (int d = 0; d < 8; ++d) {
            float gz = g0[d], g1 = G1[d], ga = G3a[d], gb = G3b[d];
            float y2 = fmaf(gz, w20, fmaf(g1, w21, bb2));
            s2 += fmaxf(y2, 0.f);
            float y3 = fmaf(gz, w30, fmaf(ga, w31, fmaf(gb, w32, bb3)));
            s3 += fmaxf(y3, 0.f);
            float z2 = fmaf(gz, u20, fmaf(g1, u21, cc2));
            t2 += fmaxf(z2, 0.f);
            float z3 = fmaf(gz, u30, fmaf(ga, u31, fmaf(gb, u32, cc3)));
            t3 += fmaxf(z3, 0.f);
        }
        if (r < 15) {
            mo_s[wid][r][k]      = s2 * 0.125f;
            mo_s[wid][r][16 + k] = s3 * 0.125f;
            mo_s[wid][r][32 + k] = t2 * 0.125f;
            mo_s[wid][r][48 + k] = t3 * 0.125f;
        }
    }
    __syncthreads();

    // stage 2: x head. lane=(r-group, do); two halves cover r=0..15 (15 masked).
    float xa = 0.f;
    #pragma unroll
    for (int half = 0; half < 2; ++half) {
        int r   = (lane >> 3) + half * 8;
        int doo = lane & 7;
        float s = 0.f;
        if (r < 15) {
            s = bzm_s[doo];
            #pragma unroll
            for (int cc = 0; cc < 8; ++cc) {
                float4 v = *(const float4*)&mo_s[wid][r][cc * 4];
                s = fmaf(v.x, wmx_s[cc * 4 + 0][doo], s);
                s = fmaf(v.y, wmx_s[cc * 4 + 1][doo], s);
                s = fmaf(v.z, wmx_s[cc * 4 + 2][doo], s);
                s = fmaf(v.w, wmx_s[cc * 4 + 3][doo], s);
            }
            s = fmaxf(s, 0.f);
        }
        xa += s;
    }
    xa += __shfl_xor(xa, 8);
    xa += __shfl_xor(xa, 16);
    xa += __shfl_xor(xa, 32);
    float xv = xa * (1.0f / 15.0f);
    if (lane < 8) xout[(long)pn * 8 + lane] = xv;

    // stage 3: z head. lane = nm; broadcast float4 reads of v-moments.
    float za = 0.f;
    #pragma unroll 1
    for (int r = 0; r < 15; ++r) {
        const float* row = &mo_s[wid][r][32];
        float s = bz3;
        #pragma unroll
        for (int cc = 0; cc < 8; ++cc) {
            float4 v = *(const float4*)(row + cc * 4);
            s = fmaf(v.x, wvx[cc * 4 + 0], s);
            s = fmaf(v.y, wvx[cc * 4 + 1], s);
            s = fmaf(v.z, wvx[cc * 4 + 2], s);
            s = fmaf(v.w, wvx[cc * 4 + 3], s);
        }
        za += fmaxf(s, 0.f);
    }
    za *= (1.0f / 61440.0f);

    zpart[wid][lane] = za;
    __syncthreads();
    if (wid == 0) {
        float ssum = zpart[0][lane] + zpart[1][lane] + zpart[2][lane] + zpart[3][lane];
        atomicAdd(&zout[b * 64 + lane], ssum);
    }
}

// ---------- launcher ----------

extern "C" void kernel_launch(void* const* d_in, const int* in_sizes, int n_in,
                              void* d_out, int out_size, void* d_ws, size_t ws_size,
                              hipStream_t stream) {
    const float* x   = (const float*)d_in[0];
    const float* z   = (const float*)d_in[1];
    const float* Wm2 = (const float*)d_in[2];
    const float* bm2 = (const float*)d_in[3];
    const float* Wm3 = (const float*)d_in[4];
    const float* bm3 = (const float*)d_in[5];
    const float* Wv2 = (const float*)d_in[6];
    const float* bv2 = (const float*)d_in[7];
    const float* Wv3 = (const float*)d_in[8];
    const float* bv3 = (const float*)d_in[9];
    const float* Wmx = (const float*)d_in[10];
    const float* bmx = (const float*)d_in[11];
    const float* Wvx = (const float*)d_in[12];
    const float* bvx = (const float*)d_in[13];
    const float* Wmz = (const float*)d_in[14];
    const float* bmz = (const float*)d_in[15];
    const float* Wvz = (const float*)d_in[16];
    const float* bvz = (const float*)d_in[17];

    float* out  = (float*)d_out;
    int*   idxw = (int*)d_ws;                                   // 1 MB
    float* zzm  = (float*)((char*)d_ws + (size_t)BB * NPP * 16 * 4);
    float* zzv  = zzm + BB * 8;
    float* n2t  = zzv + BB * 64;                                // 64 KB
    float* xout = out;                 // B*NP*8 = 131072 floats
    float* zout = out + BB * NPP * 8;  // B*64 = 256 floats

    n2_kernel<<<dim3(BB * NPP / 256), dim3(256), 0, stream>>>(
        x, z, Wmz, bmz, Wvz, bvz, n2t, zzm, zzv, zout);
    knn_kernel<<<dim3(BB * NPP / (4 * NQ)), dim3(256), 0, stream>>>(x, n2t, idxw);
    feat_kernel<<<dim3(4096), dim3(256), 0, stream>>>(
        x, idxw, Wm2, bm2, Wm3, bm3, Wv2, bv2, Wv3, bv3,
        Wmx, bmx, Wvx, bvx, zzm, zzv, xout, zout);
}

// Round 8
// 241.102 us; speedup vs baseline: 1.0741x; 1.0741x over previous
//
#include <hip/hip_runtime.h>
#include <hip/hip_bf16.h>

#define BIGF 99999999.0f
#define NPP 4096
#define BB 4
#define NQ 4
#define CAP 128

typedef float f32x2 __attribute__((ext_vector_type(2)));

// packed fp32 fma: d = a*b + c elementwise on a 2-wide register pair.
__device__ __forceinline__ f32x2 pk_fma(f32x2 a, f32x2 b, f32x2 c) {
    f32x2 d;
    asm("v_pk_fma_f32 %0, %1, %2, %3" : "=v"(d) : "v"(a), "v"(b), "v"(c));
    return d;
}

// ---------- helpers ----------

template <typename T>
__device__ __forceinline__ T bitonic_sort64(T v, int lane) {
    #pragma unroll
    for (int k = 2; k <= 64; k <<= 1) {
        #pragma unroll
        for (int j = k >> 1; j > 0; j >>= 1) {
            T p = __shfl_xor(v, j);
            bool up  = ((lane & k) == 0);
            bool low = ((lane & j) == 0);
            T mn = (v < p) ? v : p;
            T mx = (v < p) ? p : v;
            v = (up == low) ? mn : mx;
        }
    }
    return v;
}

// dot8 via 4 packed fmas + horizontal add. Deterministic expression tree:
// identical in pass A and pass B -> identical key bits.
__device__ __forceinline__ float dot8_pk(const f32x2* qp, f32x2 p0, f32x2 p1,
                                         f32x2 p2, f32x2 p3) {
    f32x2 acc = {0.f, 0.f};
    acc = pk_fma(qp[0], p0, acc);
    acc = pk_fma(qp[1], p1, acc);
    acc = pk_fma(qp[2], p2, acc);
    acc = pk_fma(qp[3], p3, acc);
    return acc.x + acc.y;
}

// ---------- kernel 0: per-point squared norms + z projections + zero zout ----------

__global__ __launch_bounds__(256) void n2_kernel(
    const float* __restrict__ x, const float* __restrict__ z,
    const float* __restrict__ Wmz, const float* __restrict__ bmz,
    const float* __restrict__ Wvz, const float* __restrict__ bvz,
    float* __restrict__ n2tab, float* __restrict__ zzm, float* __restrict__ zzv,
    float* __restrict__ zout)
{
    int i = blockIdx.x * 256 + threadIdx.x;       // 0..16383
    const float4* p = (const float4*)(x + (long)i * 8);
    float4 a = p[0], c = p[1];
    float s = 0.f;
    s = fmaf(a.x, a.x, s); s = fmaf(a.y, a.y, s);
    s = fmaf(a.z, a.z, s); s = fmaf(a.w, a.w, s);
    s = fmaf(c.x, c.x, s); s = fmaf(c.y, c.y, s);
    s = fmaf(c.z, c.z, s); s = fmaf(c.w, c.w, s);
    n2tab[i] = s;

    if (blockIdx.x == 0) {
        zout[threadIdx.x] = 0.f;                  // 256 floats
        int b = threadIdx.x >> 6, l = threadIdx.x & 63;
        float sv = 0.f;
        for (int q = 0; q < 64; ++q) sv = fmaf(z[b * 64 + q], Wvz[q * 64 + l], sv);
        zzv[b * 64 + l] = sv + bvz[l];
        if (threadIdx.x < 32) {
            int bm = threadIdx.x >> 3, lm = threadIdx.x & 7;
            float sm = 0.f;
            for (int q = 0; q < 64; ++q) sm = fmaf(z[bm * 64 + q], Wmz[q * 8 + lm], sm);
            zzm[bm * 8 + lm] = sm + bmz[lm];
        }
    }
}

// ---------- kernel 1: exact knn top-16, NQ=4 queries per wave ----------
// Pass A: per-lane u32 key min over the lane's 64-candidate substream;
// u32 bitonic sort of the 64 lane-minima -> T = 16th smallest (16 distinct
// lane witnesses <= T, so {key <= T} contains the exact top-16).
// Pass B: recompute keys (identical expression tree), wave __any early-out,
// rare LDS atomic-append of (key<<32)|j; final u64 bitonic sort (2-chunk
// merge if count>64) -> exact top-16 ascending, reference tie order.

__global__ __launch_bounds__(256) void knn_kernel(const float* __restrict__ x,
                                                  const float* __restrict__ n2tab,
                                                  int* __restrict__ idx_out) {
    __shared__ unsigned long long cand[4][NQ][CAP];   // 16 KB
    __shared__ unsigned cnt_s[4][NQ];

    int lane = threadIdx.x & 63;
    int wid  = threadIdx.x >> 6;
    if (lane < NQ) cnt_s[wid][lane] = 0;              // per-wave buffer

    int gw   = blockIdx.x * 4 + wid;      // 0..4095
    int q0   = gw * NQ;
    int b    = q0 >> 12;
    int qloc = q0 & 4095;
    const float* xb = x + (long)b * NPP * 8;
    const float* nb = n2tab + b * NPP;

    f32x2 qp[NQ][4];
    float n2i[NQ];
    int selfT[NQ], selfL[NQ];
    #pragma unroll
    for (int q = 0; q < NQ; ++q) {
        const f32x2* qsrc = (const f32x2*)(xb + (long)(qloc + q) * 8);
        #pragma unroll
        for (int e = 0; e < 4; ++e) qp[q][e] = qsrc[e];
        n2i[q]   = nb[qloc + q];
        selfT[q] = (qloc + q) >> 6;
        selfL[q] = (qloc + q) & 63;
    }
    const unsigned BIGB = __float_as_uint(BIGF);

    // ---- pass A: per-lane u32 key min ----
    unsigned minb[NQ];
    #pragma unroll
    for (int q = 0; q < NQ; ++q) minb[q] = 0xFFFFFFFFu;

    #pragma unroll 4
    for (int t = 0; t < 64; ++t) {
        int j = t * 64 + lane;
        const f32x2* pj = (const f32x2*)(xb + (long)j * 8);
        f32x2 p0 = pj[0], p1 = pj[1], p2 = pj[2], p3 = pj[3];
        float n2j = nb[j];
        #pragma unroll
        for (int q = 0; q < NQ; ++q) {
            float dot = dot8_pk(qp[q], p0, p1, p2, p3);
            float d2  = fmaf(-2.0f, dot, n2i[q] + n2j);
            unsigned kb = (d2 <= 0.0f) ? BIGB : __float_as_uint(d2);
            if (t == selfT[q]) {                       // uniform, 1-in-64
                kb = (lane == selfL[q]) ? BIGB : kb;
            }
            minb[q] = (kb < minb[q]) ? kb : minb[q];
        }
    }

    // thresholds: 16th smallest of the 64 lane minima
    unsigned T[NQ];
    #pragma unroll
    for (int q = 0; q < NQ; ++q) {
        unsigned s = bitonic_sort64(minb[q], lane);
        T[q] = (unsigned)__shfl((int)s, 15);
    }

    // ---- pass B: recompute + rare atomic append ----
    #pragma unroll 4
    for (int t = 0; t < 64; ++t) {
        int j = t * 64 + lane;
        const f32x2* pj = (const f32x2*)(xb + (long)j * 8);
        f32x2 p0 = pj[0], p1 = pj[1], p2 = pj[2], p3 = pj[3];
        float n2j = nb[j];
        unsigned kb[NQ];
        bool hit = false;
        #pragma unroll
        for (int q = 0; q < NQ; ++q) {
            float dot = dot8_pk(qp[q], p0, p1, p2, p3);
            float d2  = fmaf(-2.0f, dot, n2i[q] + n2j);
            unsigned k = (d2 <= 0.0f) ? BIGB : __float_as_uint(d2);
            if (t == selfT[q]) {
                k = (lane == selfL[q]) ? BIGB : k;
            }
            kb[q] = k;
            hit |= (k <= T[q]);
        }
        if (__any(hit)) {
            #pragma unroll
            for (int q = 0; q < NQ; ++q) {
                if (kb[q] <= T[q]) {
                    unsigned old = atomicAdd(&cnt_s[wid][q], 1u);
                    if (old < CAP) {
                        cand[wid][q][old] =
                            ((unsigned long long)kb[q] << 32) | (unsigned)j;
                    }
                }
            }
        }
    }

    // ---- final: sort candidates, emit top-16 (append order irrelevant) ----
    #pragma unroll 1
    for (int q = 0; q < NQ; ++q) {
        unsigned nc = cnt_s[wid][q];
        int n = nc > CAP ? CAP : (int)nc;
        unsigned long long v = (lane < n) ? cand[wid][q][lane] : ~0ull;
        unsigned long long R = bitonic_sort64(v, lane);
        if (n > 64) {                                   // rare 2nd chunk
            unsigned long long w2 = (64 + lane < n) ? cand[wid][q][64 + lane] : ~0ull;
            w2 = bitonic_sort64(w2, lane);
            unsigned long long vt = __shfl(w2, lane - 16);
            unsigned long long comb = (lane < 16) ? R : ((lane < 32) ? vt : ~0ull);
            R = bitonic_sort64(comb, lane);
        }
        if (lane < 16) {
            idx_out[(long)(q0 + q) * 16 + lane] = (int)(R & 0xFFFFFFFFull);
        }
    }
}

// ---------- kernel 2: features + output heads (LDS-op reduced, all fp32) ----------
// Stage1: neighbor rows via float4 (b128). Stage2: x-head with transposed
// weight rows (b128). Stage3: z-head split across half-waves — each lane owns
// 2 nm columns and half the rows; reads halve, finish with shfl_xor(32).

__global__ __launch_bounds__(256) void feat_kernel(
    const float* __restrict__ x, const int* __restrict__ idxw,
    const float* __restrict__ Wm2, const float* __restrict__ bm2,
    const float* __restrict__ Wm3, const float* __restrict__ bm3,
    const float* __restrict__ Wv2, const float* __restrict__ bv2,
    const float* __restrict__ Wv3, const float* __restrict__ bv3,
    const float* __restrict__ Wmx, const float* __restrict__ bmx,
    const float* __restrict__ Wvx, const float* __restrict__ bvx,
    const float* __restrict__ zzm, const float* __restrict__ zzv,
    float* __restrict__ xout, float* __restrict__ zout)
{
    int lane = threadIdx.x & 63;
    int wid  = threadIdx.x >> 6;
    int pn   = blockIdx.x * 4 + wid;          // global point id
    int b    = pn >> 12;
    const float* xb = x + b * NPP * 8;

    __shared__ float xg_s[4][16][8];
    __shared__ float mo_s[4][15][68];         // cols 0..31 m-moments, 32..63 v-moments
    __shared__ float wmxT_s[8][36];           // wmxT[do][c] = Wmx[c][do]
    __shared__ float bzm_s[8];
    __shared__ float zpart[4][64];

    if (threadIdx.x < 256) {
        wmxT_s[threadIdx.x & 7][threadIdx.x >> 3] = Wmx[threadIdx.x];
    }
    if (threadIdx.x < 8) bzm_s[threadIdx.x] = bmx[threadIdx.x] + zzm[b * 8 + threadIdx.x];

    int k = lane & 15;
    float w20 = Wm2[k], w21 = Wm2[16 + k], bb2 = bm2[k];
    float w30 = Wm3[k], w31 = Wm3[16 + k], w32 = Wm3[32 + k], bb3 = bm3[k];
    float u20 = Wv2[k], u21 = Wv2[16 + k], cc2 = bv2[k];
    float u30 = Wv3[k], u31 = Wv3[16 + k], u32 = Wv3[32 + k], cc3 = bv3[k];

    // stage-3 weights: lane = (g, nm) owns nm and nm+32
    int g  = lane >> 5;
    int nm = lane & 31;
    float wvxa[32], wvxb[32];
    #pragma unroll
    for (int c = 0; c < 32; ++c) {
        wvxa[c] = Wvx[c * 64 + nm];
        wvxb[c] = Wvx[c * 64 + nm + 32];
    }
    float bz3a = bvx[nm]      + zzv[b * 64 + nm];
    float bz3b = bvx[nm + 32] + zzv[b * 64 + nm + 32];

    if (lane < 16) {
        int myid = idxw[(long)pn * 16 + lane];
        const float4* ps = (const float4*)(xb + (long)myid * 8);
        float4 a = ps[0], c4 = ps[1];
        *((float4*)&xg_s[wid][lane][0]) = a;
        *((float4*)&xg_s[wid][lane][4]) = c4;
    }
    __syncthreads();

    float4 g0l = *(const float4*)&xg_s[wid][0][0];
    float4 g0h = *(const float4*)&xg_s[wid][0][4];
    float g0[8] = {g0l.x, g0l.y, g0l.z, g0l.w, g0h.x, g0h.y, g0h.z, g0h.w};

    // stage 1: moments (mean over d folded as exact *0.125)
    #pragma unroll
    for (int p = 0; p < 4; ++p) {
        int rg = lane >> 4;
        int r  = p * 4 + rg;
        int rc = (r < 14) ? r : 14;
        int i2  = rc + 1;
        int i3a = (rc < 14) ? 1 : 2;
        int i3b = (rc < 14) ? rc + 2 : 3;
        float4 a1 = *(const float4*)&xg_s[wid][i2][0];
        float4 b1 = *(const float4*)&xg_s[wid][i2][4];
        float4 aa = *(const float4*)&xg_s[wid][i3a][0];
        float4 ba = *(const float4*)&xg_s[wid][i3a][4];
        float4 ab = *(const float4*)&xg_s[wid][i3b][0];
        float4 bb = *(const float4*)&xg_s[wid][i3b][4];
        float G1[8]  = {a1.x, a1.y, a1.z, a1.w, b1.x, b1.y, b1.z, b1.w};
        float G3a[8] = {aa.x, aa.y, aa.z, aa.w, ba.x, ba.y, ba.z, ba.w};
        float G3b[8] = {ab.x, ab.y, ab.z, ab.w, bb.x, bb.y, bb.z, bb.w};
        float s2 = 0.f, s3 = 0.f, t2 = 0.f, t3 = 0.f;
        #pragma unroll
        for (int d = 0; d < 8; ++d) {
            float gz = g0[d], g1 = G1[d], ga = G3a[d], gb = G3b[d];
            float y2 = fmaf(gz, w20, fmaf(g1, w21, bb2));
            s2 += fmaxf(y2, 0.f);
            float y3 = fmaf(gz, w30, fmaf(ga, w31, fmaf(gb, w32, bb3)));
            s3 += fmaxf(y3, 0.f);
            float z2 = fmaf(gz, u20, fmaf(g1, u21, cc2));
            t2 += fmaxf(z2, 0.f);
            float z3 = fmaf(gz, u30, fmaf(ga, u31, fmaf(gb, u32, cc3)));
            t3 += fmaxf(z3, 0.f);
        }
        if (r < 15) {
            mo_s[wid][r][k]      = s2 * 0.125f;
            mo_s[wid][r][16 + k] = s3 * 0.125f;
            mo_s[wid][r][32 + k] = t2 * 0.125f;
            mo_s[wid][r][48 + k] = t3 * 0.125f;
        }
    }
    __syncthreads();

    // stage 2: x head. lane=(r-group, do); two halves cover r=0..15 (15 masked).
    float xa = 0.f;
    #pragma unroll
    for (int half = 0; half < 2; ++half) {
        int r   = (lane >> 3) + half * 8;
        int doo = lane & 7;
        float s = 0.f;
        if (r < 15) {
            s = bzm_s[doo];
            #pragma unroll
            for (int cc = 0; cc < 8; ++cc) {
                float4 v = *(const float4*)&mo_s[wid][r][cc * 4];
                float4 w = *(const float4*)&wmxT_s[doo][cc * 4];
                s = fmaf(v.x, w.x, s);
                s = fmaf(v.y, w.y, s);
                s = fmaf(v.z, w.z, s);
                s = fmaf(v.w, w.w, s);
            }
            s = fmaxf(s, 0.f);
        }
        xa += s;
    }
    xa += __shfl_xor(xa, 8);
    xa += __shfl_xor(xa, 16);
    xa += __shfl_xor(xa, 32);
    float xv = xa * (1.0f / 15.0f);
    if (lane < 8) xout[(long)pn * 8 + lane] = xv;

    // stage 3: z head, half-wave row split. g=0: rows 0..7, g=1: rows 8..14.
    float A = 0.f, Bz = 0.f;
    #pragma unroll 1
    for (int rr = 0; rr < 8; ++rr) {
        int r = g * 8 + rr;
        if (r < 15) {
            const float* row = &mo_s[wid][r][32];
            float sa = bz3a, sb = bz3b;
            #pragma unroll
            for (int cc = 0; cc < 8; ++cc) {
                float4 v = *(const float4*)(row + cc * 4);
                sa = fmaf(v.x, wvxa[cc * 4 + 0], sa);
                sb = fmaf(v.x, wvxb[cc * 4 + 0], sb);
                sa = fmaf(v.y, wvxa[cc * 4 + 1], sa);
                sb = fmaf(v.y, wvxb[cc * 4 + 1], sb);
                sa = fmaf(v.z, wvxa[cc * 4 + 2], sa);
                sb = fmaf(v.z, wvxb[cc * 4 + 2], sb);
                sa = fmaf(v.w, wvxa[cc * 4 + 3], sa);
                sb = fmaf(v.w, wvxb[cc * 4 + 3], sb);
            }
            A  += fmaxf(sa, 0.f);
            Bz += fmaxf(sb, 0.f);
        }
    }
    A  += __shfl_xor(A, 32);
    Bz += __shfl_xor(Bz, 32);
    float za = ((g == 0) ? A : Bz) * (1.0f / 61440.0f);
    zpart[wid][lane] = za;                    // lane = g*32+nm = output index
    __syncthreads();
    if (wid == 0) {
        float ssum = zpart[0][lane] + zpart[1][lane] + zpart[2][lane] + zpart[3][lane];
        atomicAdd(&zout[b * 64 + lane], ssum);
    }
}

// ---------- launcher ----------

extern "C" void kernel_launch(void* const* d_in, const int* in_sizes, int n_in,
                              void* d_out, int out_size, void* d_ws, size_t ws_size,
                              hipStream_t stream) {
    const float* x   = (const float*)d_in[0];
    const float* z   = (const float*)d_in[1];
    const float* Wm2 = (const float*)d_in[2];
    const float* bm2 = (const float*)d_in[3];
    const float* Wm3 = (const float*)d_in[4];
    const float* bm3 = (const float*)d_in[5];
    const float* Wv2 = (const float*)d_in[6];
    const float* bv2 = (const float*)d_in[7];
    const float* Wv3 = (const float*)d_in[8];
    const float* bv3 = (const float*)d_in[9];
    const float* Wmx = (const float*)d_in[10];
    const float* bmx = (const float*)d_in[11];
    const float* Wvx = (const float*)d_in[12];
    const float* bvx = (const float*)d_in[13];
    const float* Wmz = (const float*)d_in[14];
    const float* bmz = (const float*)d_in[15];
    const float* Wvz = (const float*)d_in[16];
    const float* bvz = (const float*)d_in[17];

    float* out  = (float*)d_out;
    int*   idxw = (int*)d_ws;                                   // 1 MB
    float* zzm  = (float*)((char*)d_ws + (size_t)BB * NPP * 16 * 4);
    float* zzv  = zzm + BB * 8;
    float* n2t  = zzv + BB * 64;                                // 64 KB
    float* xout = out;                 // B*NP*8 = 131072 floats
    float* zout = out + BB * NPP * 8;  // B*64 = 256 floats

    n2_kernel<<<dim3(BB * NPP / 256), dim3(256), 0, stream>>>(
        x, z, Wmz, bmz, Wvz, bvz, n2t, zzm, zzv, zout);
    knn_kernel<<<dim3(BB * NPP / (4 * NQ)), dim3(256), 0, stream>>>(x, n2t, idxw);
    feat_kernel<<<dim3(4096), dim3(256), 0, stream>>>(
        x, idxw, Wm2, bm2, Wm3, bm3, Wv2, bv2, Wv3, bv3,
        Wmx, bmx, Wvx, bvx, zzm, zzv, xout, zout);
}

// Round 9
// 217.634 us; speedup vs baseline: 1.1899x; 1.1078x over previous
//
#include <hip/hip_runtime.h>
#include <hip/hip_bf16.h>

#define NPP 4096
#define BB 4
#define NQ 4
#define CAP 128

typedef float f32x2 __attribute__((ext_vector_type(2)));
typedef unsigned long long u64;

// packed fp32 fma: d = a*b + c elementwise on a 2-wide register pair.
__device__ __forceinline__ f32x2 pk_fma(f32x2 a, f32x2 b, f32x2 c) {
    f32x2 d;
    asm("v_pk_fma_f32 %0, %1, %2, %3" : "=v"(d) : "v"(a), "v"(b), "v"(c));
    return d;
}

template <typename T>
__device__ __forceinline__ T bitonic_sort64(T v, int lane) {
    #pragma unroll
    for (int k = 2; k <= 64; k <<= 1) {
        #pragma unroll
        for (int j = k >> 1; j > 0; j >>= 1) {
            T p = __shfl_xor(v, j);
            bool up  = ((lane & k) == 0);
            bool low = ((lane & j) == 0);
            T mn = (v < p) ? v : p;
            T mx = (v < p) ? p : v;
            v = (up == low) ? mn : mx;
        }
    }
    return v;
}

// dot8 via 4 packed fmas + horizontal add. Deterministic expression tree:
// identical in pass A and pass B -> identical key bits.
__device__ __forceinline__ float dot8_pk(const f32x2* qp, f32x2 p0, f32x2 p1,
                                         f32x2 p2, f32x2 p3) {
    f32x2 acc = {0.f, 0.f};
    acc = pk_fma(qp[0], p0, acc);
    acc = pk_fma(qp[1], p1, acc);
    acc = pk_fma(qp[2], p2, acc);
    acc = pk_fma(qp[3], p3, acc);
    return acc.x + acc.y;
}

// ---------- kernel 0: squared norms + z projections + zero zout ----------

__global__ __launch_bounds__(256) void n2_kernel(
    const float* __restrict__ x, const float* __restrict__ z,
    const float* __restrict__ Wmz, const float* __restrict__ bmz,
    const float* __restrict__ Wvz, const float* __restrict__ bvz,
    float* __restrict__ n2tab, float* __restrict__ zzm, float* __restrict__ zzv,
    float* __restrict__ zout)
{
    int i = blockIdx.x * 256 + threadIdx.x;       // 0..16383
    const float4* p = (const float4*)(x + (long)i * 8);
    float4 a = p[0], c = p[1];
    float s = 0.f;
    s = fmaf(a.x, a.x, s); s = fmaf(a.y, a.y, s);
    s = fmaf(a.z, a.z, s); s = fmaf(a.w, a.w, s);
    s = fmaf(c.x, c.x, s); s = fmaf(c.y, c.y, s);
    s = fmaf(c.z, c.z, s); s = fmaf(c.w, c.w, s);
    n2tab[i] = s;

    if (blockIdx.x == 0) {
        zout[threadIdx.x] = 0.f;                  // 256 floats
        int b = threadIdx.x >> 6, l = threadIdx.x & 63;
        float sv = 0.f;
        for (int q = 0; q < 64; ++q) sv = fmaf(z[b * 64 + q], Wvz[q * 64 + l], sv);
        zzv[b * 64 + l] = sv + bvz[l];
        if (threadIdx.x < 32) {
            int bm = threadIdx.x >> 3, lm = threadIdx.x & 7;
            float sm = 0.f;
            for (int q = 0; q < 64; ++q) sm = fmaf(z[bm * 64 + q], Wmz[q * 8 + lm], sm);
            zzm[bm * 8 + lm] = sm + bmz[lm];
        }
    }
}

// ---------- fused kernel: exact knn top-16 + features + heads ----------
// Pass A (half-sampled, t even): per-lane u32 key min over a 32-candidate
// disjoint substream; T = 16th smallest of the 64 lane minima -> 16 distinct
// witnesses with key <= T, so {key <= T} contains the exact top-16.
// Negative-d2 keys have bit >= 0x80000000 -> auto-excluded (reference maps
// d2<=0 to BIG too); self patched explicitly. Pass B: full scan, append
// (key<<32)|j for key<=T (LDS atomic), u64 bitonic sort (+2-chunk merge),
// lanes 0..15 hold the exact sorted top-16. Then the SAME wave runs the
// feature pipeline for its 4 points (no global roundtrip, no extra launch).

__global__ __launch_bounds__(256) void fused_kernel(
    const float* __restrict__ x, const float* __restrict__ n2tab,
    const float* __restrict__ Wm2, const float* __restrict__ bm2,
    const float* __restrict__ Wm3, const float* __restrict__ bm3,
    const float* __restrict__ Wv2, const float* __restrict__ bv2,
    const float* __restrict__ Wv3, const float* __restrict__ bv3,
    const float* __restrict__ Wmx, const float* __restrict__ bmx,
    const float* __restrict__ Wvx, const float* __restrict__ bvx,
    const float* __restrict__ zzm, const float* __restrict__ zzv,
    float* __restrict__ xout, float* __restrict__ zout)
{
    // per-wave union: knn candidate buffer (NQ*CAP*8 = 4096B), later reused
    // as the moment matrix mo[15][72] (4320B). 4352B per wave, 16B aligned.
    __shared__ __align__(16) char ubuf[4][4352];
    __shared__ float xg_s[4][NQ][16][8];      // gathered neighbors (8 KB)
    __shared__ int   idx_s[4][NQ][16];        // sorted top-16 indices (1 KB)
    __shared__ float wmxT_s[8][40];           // Wmx transposed, 16B rows
    __shared__ float bzm_s[8];
    __shared__ float zpart[4][64];
    __shared__ unsigned cnt_s[4][NQ];

    int lane = threadIdx.x & 63;
    int wid  = threadIdx.x >> 6;
    int gw   = blockIdx.x * 4 + wid;      // 0..4095
    int q0   = gw * NQ;
    int b    = q0 >> 12;                  // block-uniform (256 blocks/batch)
    int qloc = q0 & 4095;
    const float* xb = x + (long)b * NPP * 8;
    const float* nb = n2tab + b * NPP;

    if (threadIdx.x < 256) wmxT_s[threadIdx.x & 7][threadIdx.x >> 3] = Wmx[threadIdx.x];
    if (threadIdx.x < 8)   bzm_s[threadIdx.x] = bmx[threadIdx.x] + zzm[b * 8 + threadIdx.x];
    if (lane < NQ) cnt_s[wid][lane] = 0;
    __syncthreads();

    // ---- queries ----
    f32x2 qp[NQ][4];
    float n2i[NQ];
    int selfT[NQ], selfL[NQ];
    #pragma unroll
    for (int q = 0; q < NQ; ++q) {
        const f32x2* qsrc = (const f32x2*)(xb + (long)(qloc + q) * 8);
        #pragma unroll
        for (int e = 0; e < 4; ++e) qp[q][e] = qsrc[e];
        n2i[q]   = nb[qloc + q];
        selfT[q] = (qloc + q) >> 6;
        selfL[q] = (qloc + q) & 63;
    }

    // ---- pass A: half-sampled per-lane key min ----
    unsigned minb[NQ];
    #pragma unroll
    for (int q = 0; q < NQ; ++q) minb[q] = 0xFFFFFFFFu;

    #pragma unroll 4
    for (int tt = 0; tt < 32; ++tt) {
        int t = tt * 2;
        int j = t * 64 + lane;
        const f32x2* pj = (const f32x2*)(xb + (long)j * 8);
        f32x2 p0 = pj[0], p1 = pj[1], p2 = pj[2], p3 = pj[3];
        float n2j = nb[j];
        #pragma unroll
        for (int q = 0; q < NQ; ++q) {
            float dot = dot8_pk(qp[q], p0, p1, p2, p3);
            float d2  = fmaf(-2.0f, dot, n2i[q] + n2j);
            unsigned kb = __float_as_uint(d2);          // d2<0 -> >=0x80000000 (auto-big)
            if (t == selfT[q]) kb = (lane == selfL[q]) ? 0xFFFFFFFFu : kb;
            minb[q] = (kb < minb[q]) ? kb : minb[q];
        }
    }

    unsigned T[NQ];
    #pragma unroll
    for (int q = 0; q < NQ; ++q) {
        unsigned s = bitonic_sort64(minb[q], lane);
        T[q] = (unsigned)__shfl((int)s, 15);
    }

    // ---- pass B: full scan + rare atomic append ----
    u64* cand = (u64*)ubuf[wid];          // [q*CAP + i]
    #pragma unroll 2
    for (int t = 0; t < 64; ++t) {
        int j = t * 64 + lane;
        const f32x2* pj = (const f32x2*)(xb + (long)j * 8);
        f32x2 p0 = pj[0], p1 = pj[1], p2 = pj[2], p3 = pj[3];
        float n2j = nb[j];
        #pragma unroll
        for (int q = 0; q < NQ; ++q) {
            float dot = dot8_pk(qp[q], p0, p1, p2, p3);
            float d2  = fmaf(-2.0f, dot, n2i[q] + n2j);
            unsigned kb = __float_as_uint(d2);
            if (t == selfT[q]) kb = (lane == selfL[q]) ? 0xFFFFFFFFu : kb;
            if (kb <= T[q]) {
                unsigned old = atomicAdd(&cnt_s[wid][q], 1u);
                if (old < CAP) cand[q * CAP + old] = ((u64)kb << 32) | (unsigned)j;
            }
        }
    }

    // ---- sort candidates, keep exact top-16 (append order irrelevant) ----
    #pragma unroll 1
    for (int q = 0; q < NQ; ++q) {
        unsigned nc = cnt_s[wid][q];
        int n = nc > CAP ? CAP : (int)nc;
        u64 v = (lane < n) ? cand[q * CAP + lane] : ~0ull;
        u64 R = bitonic_sort64(v, lane);
        if (n > 64) {                                   // rare (~1% of queries)
            u64 w2 = (64 + lane < n) ? cand[q * CAP + 64 + lane] : ~0ull;
            w2 = bitonic_sort64(w2, lane);
            u64 vt = __shfl(w2, lane - 16);
            u64 comb = (lane < 16) ? R : ((lane < 32) ? vt : ~0ull);
            R = bitonic_sort64(comb, lane);
        }
        if (lane < 16) idx_s[wid][q][lane] = (int)(R & 0xFFFFFFFFull);
    }

    // ---- gather all 4 points' neighbors (overlapped latency) ----
    #pragma unroll
    for (int p = 0; p < NQ; ++p) {
        if (lane < 16) {
            int id = idx_s[wid][p][lane];
            const float4* ps = (const float4*)(xb + (long)id * 8);
            float4 A = ps[0], C = ps[1];
            *((float4*)&xg_s[wid][p][lane][0]) = A;
            *((float4*)&xg_s[wid][p][lane][4]) = C;
        }
    }

    // ---- feature weights ----
    int k = lane & 15;
    float w20 = Wm2[k], w21 = Wm2[16 + k], bb2 = bm2[k];
    float w30 = Wm3[k], w31 = Wm3[16 + k], w32 = Wm3[32 + k], bb3 = bm3[k];
    float u20 = Wv2[k], u21 = Wv2[16 + k], cc2 = bv2[k];
    float u30 = Wv3[k], u31 = Wv3[16 + k], u32 = Wv3[32 + k], cc3 = bv3[k];

    int g  = lane >> 5;
    int nm = lane & 31;
    f32x2 wa2[16], wb2[16];
    #pragma unroll
    for (int cc = 0; cc < 16; ++cc) {
        wa2[cc].x = Wvx[(2 * cc) * 64 + nm];
        wa2[cc].y = Wvx[(2 * cc + 1) * 64 + nm];
        wb2[cc].x = Wvx[(2 * cc) * 64 + nm + 32];
        wb2[cc].y = Wvx[(2 * cc + 1) * 64 + nm + 32];
    }
    float bz3a = bvx[nm]      + zzv[b * 64 + nm];
    float bz3b = bvx[nm + 32] + zzv[b * 64 + nm + 32];

    float* mo = (float*)ubuf[wid];        // [r*72 + c]  (aliases cand: done)
    float Aacc = 0.f, Bacc = 0.f;

    #pragma unroll 1
    for (int p = 0; p < NQ; ++p) {
        float4 g0l = *(const float4*)&xg_s[wid][p][0][0];
        float4 g0h = *(const float4*)&xg_s[wid][p][0][4];
        float g0[8] = {g0l.x, g0l.y, g0l.z, g0l.w, g0h.x, g0h.y, g0h.z, g0h.w};

        // stage 1: moments (mean over d folded as exact *0.125)
        #pragma unroll
        for (int pp = 0; pp < 4; ++pp) {
            int rg = lane >> 4;
            int r  = pp * 4 + rg;
            int rc = (r < 14) ? r : 14;
            int i2  = rc + 1;
            int i3a = (rc < 14) ? 1 : 2;
            int i3b = (rc < 14) ? rc + 2 : 3;
            float4 a1 = *(const float4*)&xg_s[wid][p][i2][0];
            float4 b1 = *(const float4*)&xg_s[wid][p][i2][4];
            float4 aa = *(const float4*)&xg_s[wid][p][i3a][0];
            float4 ba = *(const float4*)&xg_s[wid][p][i3a][4];
            float4 ab = *(const float4*)&xg_s[wid][p][i3b][0];
            float4 bb = *(const float4*)&xg_s[wid][p][i3b][4];
            float G1[8]  = {a1.x, a1.y, a1.z, a1.w, b1.x, b1.y, b1.z, b1.w};
            float G3a[8] = {aa.x, aa.y, aa.z, aa.w, ba.x, ba.y, ba.z, ba.w};
            float G3b[8] = {ab.x, ab.y, ab.z, ab.w, bb.x, bb.y, bb.z, bb.w};
            float s2 = 0.f, s3 = 0.f, t2 = 0.f, t3 = 0.f;
            #pragma unroll
            for (int d = 0; d < 8; ++d) {
                float gz = g0[d], g1 = G1[d], ga = G3a[d], gb = G3b[d];
                float y2 = fmaf(gz, w20, fmaf(g1, w21, bb2));
                s2 += fmaxf(y2, 0.f);
                float y3 = fmaf(gz, w30, fmaf(ga, w31, fmaf(gb, w32, bb3)));
                s3 += fmaxf(y3, 0.f);
                float z2 = fmaf(gz, u20, fmaf(g1, u21, cc2));
                t2 += fmaxf(z2, 0.f);
                float z3 = fmaf(gz, u30, fmaf(ga, u31, fmaf(gb, u32, cc3)));
                t3 += fmaxf(z3, 0.f);
            }
            if (r < 15) {
                mo[r * 72 + k]      = s2 * 0.125f;
                mo[r * 72 + 16 + k] = s3 * 0.125f;
                mo[r * 72 + 32 + k] = t2 * 0.125f;
                mo[r * 72 + 48 + k] = t3 * 0.125f;
            }
        }

        // stage 2: x head (packed fma over c-pairs)
        float xa = 0.f;
        #pragma unroll
        for (int half = 0; half < 2; ++half) {
            int r   = (lane >> 3) + half * 8;
            int doo = lane & 7;
            if (r < 15) {
                const f32x2* vp = (const f32x2*)&mo[r * 72];
                const f32x2* wp = (const f32x2*)&wmxT_s[doo][0];
                f32x2 acc = {0.f, 0.f};
                #pragma unroll
                for (int cc = 0; cc < 16; ++cc) acc = pk_fma(vp[cc], wp[cc], acc);
                float s = bzm_s[doo] + acc.x + acc.y;
                xa += fmaxf(s, 0.f);
            }
        }
        xa += __shfl_xor(xa, 8);
        xa += __shfl_xor(xa, 16);
        xa += __shfl_xor(xa, 32);
        if (lane < 8) xout[(long)(q0 + p) * 8 + lane] = xa * (1.0f / 15.0f);

        // stage 3: z head (packed, half-wave row split; accumulate across p)
        #pragma unroll 1
        for (int rr = 0; rr < 8; ++rr) {
            int r = g * 8 + rr;
            if (r < 15) {
                const f32x2* vp = (const f32x2*)&mo[r * 72 + 32];
                f32x2 accA = {0.f, 0.f}, accB = {0.f, 0.f};
                #pragma unroll
                for (int cc = 0; cc < 16; ++cc) {
                    f32x2 v = vp[cc];
                    accA = pk_fma(v, wa2[cc], accA);
                    accB = pk_fma(v, wb2[cc], accB);
                }
                float sa = bz3a + accA.x + accA.y;
                float sb = bz3b + accB.x + accB.y;
                Aacc += fmaxf(sa, 0.f);
                Bacc += fmaxf(sb, 0.f);
            }
        }
    }

    Aacc += __shfl_xor(Aacc, 32);
    Bacc += __shfl_xor(Bacc, 32);
    float za = ((g == 0) ? Aacc : Bacc) * (1.0f / 61440.0f);
    zpart[wid][lane] = za;                // lane = g*32+nm = output index
    __syncthreads();
    if (wid == 0) {
        float ssum = zpart[0][lane] + zpart[1][lane] + zpart[2][lane] + zpart[3][lane];
        atomicAdd(&zout[b * 64 + lane], ssum);
    }
}

// ---------- launcher ----------

extern "C" void kernel_launch(void* const* d_in, const int* in_sizes, int n_in,
                              void* d_out, int out_size, void* d_ws, size_t ws_size,
                              hipStream_t stream) {
    const float* x   = (const float*)d_in[0];
    const float* z   = (const float*)d_in[1];
    const float* Wm2 = (const float*)d_in[2];
    const float* bm2 = (const float*)d_in[3];
    const float* Wm3 = (const float*)d_in[4];
    const float* bm3 = (const float*)d_in[5];
    const float* Wv2 = (const float*)d_in[6];
    const float* bv2 = (const float*)d_in[7];
    const float* Wv3 = (const float*)d_in[8];
    const float* bv3 = (const float*)d_in[9];
    const float* Wmx = (const float*)d_in[10];
    const float* bmx = (const float*)d_in[11];
    const float* Wvx = (const float*)d_in[12];
    const float* bvx = (const float*)d_in[13];
    const float* Wmz = (const float*)d_in[14];
    const float* bmz = (const float*)d_in[15];
    const float* Wvz = (const float*)d_in[16];
    const float* bvz = (const float*)d_in[17];

    float* out  = (float*)d_out;
    float* zzm  = (float*)d_ws;                 // 32 floats
    float* zzv  = zzm + 32;                     // 256 floats
    float* n2t  = zzv + 256;                    // 16384 floats
    float* xout = out;                          // B*NP*8 = 131072 floats
    float* zout = out + BB * NPP * 8;           // B*64 = 256 floats

    n2_kernel<<<dim3(BB * NPP / 256), dim3(256), 0, stream>>>(
        x, z, Wmz, bmz, Wvz, bvz, n2t, zzm, zzv, zout);
    fused_kernel<<<dim3(BB * NPP / (4 * NQ)), dim3(256), 0, stream>>>(
        x, n2t, Wm2, bm2, Wm3, bm3, Wv2, bv2, Wv3, bv3,
        Wmx, bmx, Wvx, bvx, zzm, zzv, xout, zout);
}